// Round 1
// baseline (515.779 us; speedup 1.0000x reference)
//
#include <hip/hip_runtime.h>

#define U_   8
#define B_   16384
#define IN_  512
#define H_   512
#define NC_  62
#define NCP_ 64

typedef __attribute__((ext_vector_type(8))) short bfrag;   // 8 bf16 (4 VGPRs)
typedef __attribute__((ext_vector_type(4))) float facc;    // 4 fp32 acc

__device__ __forceinline__ float bf2f(unsigned int lo16) {
    union { unsigned int i; float f; } v;
    v.i = lo16 << 16;
    return v.f;
}
__device__ __forceinline__ unsigned short f2bf(float f) {
    unsigned int x = __float_as_uint(f);
    // round-to-nearest-even
    return (unsigned short)((x + 0x7fffu + ((x >> 16) & 1u)) >> 16);
}

__device__ __forceinline__ void gl2lds16(const void* g, void* l) {
    // async global->LDS, 16B per lane; LDS dest = wave-uniform base + lane*16
    __builtin_amdgcn_global_load_lds(
        (const __attribute__((address_space(1))) void*)g,
        (__attribute__((address_space(3))) void*)l, 16, 0, 0);
}

// ---------------------------------------------------------------------------
// prep: normalized policies, final per-unit weights, folded output bias
// ---------------------------------------------------------------------------
__global__ void prep_kernel(const float* __restrict__ p1, const float* __restrict__ p2,
                            const float* __restrict__ pf, const float* __restrict__ b2,
                            float* __restrict__ P1n, float* __restrict__ P2n,
                            float* __restrict__ wfin, float* __restrict__ cconst)
{
    int t = threadIdx.x;
    if (t >= 64) return;
    int row = t >> 3;
    float s1 = 0.f, s2 = 0.f;
    for (int f = 0; f < 8; f++) { s1 += p1[row * 8 + f]; s2 += p2[row * 8 + f]; }
    P1n[t] = p1[t] * (s1 > 0.f ? 1.f / s1 : 1.f);
    P2n[t] = p2[t] * (s2 > 0.f ? 1.f / s2 : 1.f);
    float d = 0.f;
    for (int j = 0; j < 8; j++) d += pf[j];
    float inv = d > 0.f ? 1.f / d : 1.f;
    float wv[8];
    for (int j = 0; j < 8; j++) {
        float v = pf[j];
        for (int i = j; i < 8; i++) v *= inv;   // inv applied (8-j) times
        wv[j] = v;
    }
    if (t < 8) wfin[t] = wv[t];
    float cc = 0.f;
    if (t < NC_) for (int u = 0; u < 8; u++) cc += wv[u] * b2[u * NC_ + t];
    cconst[t] = cc;   // t in [62,64) -> 0
}

// ---------------------------------------------------------------------------
// transpose W [U][512][N] fp32 -> Wt [U][Npad][512] bf16 (optional per-u scale)
// ---------------------------------------------------------------------------
__global__ __launch_bounds__(256) void transpose_w(
    const float* __restrict__ W, unsigned short* __restrict__ Wt,
    int N, int Npad, const float* __restrict__ scale)
{
    __shared__ float tile[32][33];
    const int u  = blockIdx.z;
    const int n0 = blockIdx.x * 32, k0 = blockIdx.y * 32;
    const int tx = threadIdx.x & 31, ty = threadIdx.x >> 5;
    const float* Wb = W + (long)u * 512 * N;
#pragma unroll
    for (int i = 0; i < 4; i++) {
        int k = k0 + ty + i * 8;
        int n = n0 + tx;
        tile[ty + i * 8][tx] = (n < N) ? Wb[(long)k * N + n] : 0.f;
    }
    __syncthreads();
    const float s = scale ? scale[u] : 1.f;
    unsigned short* Wo = Wt + (long)u * Npad * 512;
#pragma unroll
    for (int i = 0; i < 4; i++) {
        int n = n0 + ty + i * 8;
        int k = k0 + tx;
        if (n < Npad) Wo[(long)n * 512 + k] = f2bf(tile[tx][ty + i * 8] * s);
    }
}

// ---------------------------------------------------------------------------
// x fp32 -> bf16, 8 elems/thread
// ---------------------------------------------------------------------------
__global__ __launch_bounds__(256) void convert_x(
    const float* __restrict__ x, unsigned short* __restrict__ xb, long n)
{
    long i = ((long)blockIdx.x * 256 + threadIdx.x) * 8;
    if (i >= n) return;
    const float4* xp = (const float4*)(x + i);
    float4 a = xp[0], b = xp[1];
    uint4 o;
    o.x = f2bf(a.x) | ((unsigned)f2bf(a.y) << 16);
    o.y = f2bf(a.z) | ((unsigned)f2bf(a.w) << 16);
    o.z = f2bf(b.x) | ((unsigned)f2bf(b.y) << 16);
    o.w = f2bf(b.z) | ((unsigned)f2bf(b.w) << 16);
    *(uint4*)(xb + i) = o;
}

// ---------------------------------------------------------------------------
// aggregate: a[t] = sum_f Pn[t][f] * h[f], planes of `plane` bf16 elems
// ---------------------------------------------------------------------------
__global__ __launch_bounds__(256) void aggregate(
    const unsigned short* __restrict__ h, unsigned short* __restrict__ a,
    const float* __restrict__ Pn, long plane)
{
    long idx = ((long)blockIdx.x * 256 + threadIdx.x) * 8;
    float av[8][8];
#pragma unroll
    for (int t = 0; t < 8; t++)
#pragma unroll
        for (int e = 0; e < 8; e++) av[t][e] = 0.f;
    float pw[64];
#pragma unroll
    for (int i = 0; i < 64; i++) pw[i] = Pn[i];   // uniform -> scalar loads
#pragma unroll
    for (int f = 0; f < 8; f++) {
        uint4 v = *(const uint4*)(h + (long)f * plane + idx);
        float xv[8] = { bf2f(v.x & 0xffff), bf2f(v.x >> 16),
                        bf2f(v.y & 0xffff), bf2f(v.y >> 16),
                        bf2f(v.z & 0xffff), bf2f(v.z >> 16),
                        bf2f(v.w & 0xffff), bf2f(v.w >> 16) };
#pragma unroll
        for (int t = 0; t < 8; t++) {
            float p = pw[t * 8 + f];
#pragma unroll
            for (int e = 0; e < 8; e++) av[t][e] = fmaf(p, xv[e], av[t][e]);
        }
    }
#pragma unroll
    for (int t = 0; t < 8; t++) {
        uint4 o;
        o.x = f2bf(av[t][0]) | ((unsigned)f2bf(av[t][1]) << 16);
        o.y = f2bf(av[t][2]) | ((unsigned)f2bf(av[t][3]) << 16);
        o.z = f2bf(av[t][4]) | ((unsigned)f2bf(av[t][5]) << 16);
        o.w = f2bf(av[t][6]) | ((unsigned)f2bf(av[t][7]) << 16);
        *(uint4*)(a + (long)t * plane + idx) = o;
    }
}

// ---------------------------------------------------------------------------
// gemm_h: C[u] = relu(A[u] @ Bt[u]^T + bias[u]), m97-style 128x128 tile, K=N=512
//   A bf16 [rows,512] (plane stride aPlane elems; 0 = shared across u)
//   Bt bf16 [U][512 n][512 k], bias fp32 [U][512], C bf16 [U][rows][512]
// ---------------------------------------------------------------------------
__global__ __launch_bounds__(256) void gemm_h(
    const unsigned short* __restrict__ A, long aPlane,
    const unsigned short* __restrict__ Bt,
    const float* __restrict__ bias,
    unsigned short* __restrict__ C, long cPlane)
{
    __shared__ __align__(16) unsigned short sA[128 * 32];
    __shared__ __align__(16) unsigned short sB[128 * 32];
    const int tid = threadIdx.x;
    const int w = tid >> 6, lane = tid & 63;
    const int u = blockIdx.z;
    const long mBase = (long)blockIdx.y * 128;
    const int nBase = blockIdx.x * 128;

    const unsigned short* Ab = A + (long)u * aPlane;
    const unsigned short* Bb = Bt + ((long)u * 512 + nBase) * 512;

    const int j0 = 2 * w, j1 = 2 * w + 1;
    const int rr0 = 16 * j0 + (lane >> 2);
    const int rr1 = 16 * j1 + (lane >> 2);
    const int c8 = (lane & 3) * 8;

    const unsigned short* gA0 = Ab + (mBase + rr0) * 512 + c8;
    const unsigned short* gA1 = Ab + (mBase + rr1) * 512 + c8;
    const unsigned short* gB0 = Bb + (long)rr0 * 512 + c8;
    const unsigned short* gB1 = Bb + (long)rr1 * 512 + c8;
    unsigned short* lA0 = sA + j0 * 512;
    unsigned short* lA1 = sA + j1 * 512;
    unsigned short* lB0 = sB + j0 * 512;
    unsigned short* lB1 = sB + j1 * 512;

    const int wm = w >> 1, wn = w & 1;
    const int r = lane & 15, q = lane >> 4;

    facc acc[4][4];
#pragma unroll
    for (int i = 0; i < 4; i++)
#pragma unroll
        for (int j = 0; j < 4; j++) acc[i][j] = (facc){0.f, 0.f, 0.f, 0.f};

    for (int k0 = 0; k0 < 512; k0 += 32) {
        __syncthreads();
        gl2lds16(gA0 + k0, lA0);
        gl2lds16(gA1 + k0, lA1);
        gl2lds16(gB0 + k0, lB0);
        gl2lds16(gB1 + k0, lB1);
        __syncthreads();
        bfrag aF[4], bF[4];
#pragma unroll
        for (int mt = 0; mt < 4; mt++)
            aF[mt] = *(const bfrag*)&sA[(wm * 64 + mt * 16 + r) * 32 + q * 8];
#pragma unroll
        for (int nt = 0; nt < 4; nt++)
            bF[nt] = *(const bfrag*)&sB[(wn * 64 + nt * 16 + r) * 32 + q * 8];
#pragma unroll
        for (int mt = 0; mt < 4; mt++)
#pragma unroll
            for (int nt = 0; nt < 4; nt++)
                acc[mt][nt] = __builtin_amdgcn_mfma_f32_16x16x32_bf16(
                    aF[mt], bF[nt], acc[mt][nt], 0, 0, 0);
    }

    const float* bu = bias + u * 512;
    unsigned short* Cb = C + (long)u * cPlane;
#pragma unroll
    for (int nt = 0; nt < 4; nt++) {
        const int col = nBase + wn * 64 + nt * 16 + r;
        const float bv = bu[col];
#pragma unroll
        for (int mt = 0; mt < 4; mt++) {
#pragma unroll
            for (int rg = 0; rg < 4; rg++) {
                const long gm = mBase + wm * 64 + mt * 16 + q * 4 + rg;
                float v = acc[mt][nt][rg] + bv;
                v = v > 0.f ? v : 0.f;
                Cb[gm * 512 + col] = f2bf(v);
            }
        }
    }
}

// ---------------------------------------------------------------------------
// gemm_out: out[b,c] = sum_{u,k} A[u][b][k] * Bt[u][c][k] + cconst[c]
//   (w[u] pre-folded into Bt, b2 pre-folded into cconst). 64x64 tile, K=8*512.
// ---------------------------------------------------------------------------
__global__ __launch_bounds__(256) void gemm_out(
    const unsigned short* __restrict__ A, long aPlane,
    const unsigned short* __restrict__ Bt,
    const float* __restrict__ cconst,
    float* __restrict__ out)
{
    __shared__ __align__(16) unsigned short sA[64 * 32];
    __shared__ __align__(16) unsigned short sB[64 * 32];
    const int tid = threadIdx.x;
    const int w = tid >> 6, lane = tid & 63;
    const long mBase = (long)blockIdx.x * 64;
    const int row = 16 * w + (lane >> 2);
    const int c8 = (lane & 3) * 8;
    const int wm = w >> 1, wn = w & 1;
    const int r = lane & 15, q = lane >> 4;

    const unsigned short* gA = A + (mBase + row) * 512 + c8;
    const unsigned short* gB = Bt + (long)row * 512 + c8;
    unsigned short* lA = sA + w * 512;
    unsigned short* lB = sB + w * 512;

    facc acc[2][2];
#pragma unroll
    for (int i = 0; i < 2; i++)
#pragma unroll
        for (int j = 0; j < 2; j++) acc[i][j] = (facc){0.f, 0.f, 0.f, 0.f};

    for (int kk = 0; kk < 128; kk++) {
        const int u = kk >> 4;
        const int kl = (kk & 15) * 32;
        __syncthreads();
        gl2lds16(gA + (long)u * aPlane + kl, lA);
        gl2lds16(gB + (long)u * (64 * 512) + kl, lB);
        __syncthreads();
        bfrag aF[2], bF[2];
#pragma unroll
        for (int mt = 0; mt < 2; mt++)
            aF[mt] = *(const bfrag*)&sA[(wm * 32 + mt * 16 + r) * 32 + q * 8];
#pragma unroll
        for (int nt = 0; nt < 2; nt++)
            bF[nt] = *(const bfrag*)&sB[(wn * 32 + nt * 16 + r) * 32 + q * 8];
#pragma unroll
        for (int mt = 0; mt < 2; mt++)
#pragma unroll
            for (int nt = 0; nt < 2; nt++)
                acc[mt][nt] = __builtin_amdgcn_mfma_f32_16x16x32_bf16(
                    aF[mt], bF[nt], acc[mt][nt], 0, 0, 0);
    }

#pragma unroll
    for (int nt = 0; nt < 2; nt++) {
        const int col = wn * 32 + nt * 16 + r;
        if (col < NC_) {
            const float cc = cconst[col];
#pragma unroll
            for (int mt = 0; mt < 2; mt++) {
#pragma unroll
                for (int rg = 0; rg < 4; rg++) {
                    const long gm = mBase + wm * 32 + mt * 16 + q * 4 + rg;
                    out[gm * NC_ + col] = acc[mt][nt][rg] + cc;
                }
            }
        }
    }
}

// ---------------------------------------------------------------------------
extern "C" void kernel_launch(void* const* d_in, const int* in_sizes, int n_in,
                              void* d_out, int out_size, void* d_ws, size_t ws_size,
                              hipStream_t stream)
{
    const float* x  = (const float*)d_in[0];
    const float* p1 = (const float*)d_in[1];
    const float* p2 = (const float*)d_in[2];
    const float* pf = (const float*)d_in[3];
    const float* W0 = (const float*)d_in[4];
    const float* b0 = (const float*)d_in[5];
    const float* W1 = (const float*)d_in[6];
    const float* b1 = (const float*)d_in[7];
    const float* W2 = (const float*)d_in[8];
    const float* b2 = (const float*)d_in[9];
    float* out = (float*)d_out;

    char* ws = (char*)d_ws;
    size_t off = 0;
    auto alloc = [&](size_t bytes) -> void* {
        void* p = ws + off;
        off += (bytes + 255) & ~(size_t)255;
        return p;
    };
    float* P1n    = (float*)alloc(64 * sizeof(float));
    float* P2n    = (float*)alloc(64 * sizeof(float));
    float* wfin   = (float*)alloc(8 * sizeof(float));
    float* cconst = (float*)alloc(64 * sizeof(float));
    unsigned short* W0t = (unsigned short*)alloc((size_t)U_ * 512 * 512 * 2);
    unsigned short* W1t = (unsigned short*)alloc((size_t)U_ * 512 * 512 * 2);
    unsigned short* W2t = (unsigned short*)alloc((size_t)U_ * NCP_ * 512 * 2);
    unsigned short* xb  = (unsigned short*)alloc((size_t)B_ * IN_ * 2);

    // pick the largest batch chunk whose two 8-unit bf16 plane buffers fit
    size_t remain = ws_size > off ? ws_size - off : 0;
    int Bc = 128;
    for (int cand = B_; cand >= 128; cand >>= 1) {
        if (2ull * U_ * (size_t)cand * 512 * 2 + 512 <= remain) { Bc = cand; break; }
    }
    unsigned short* bufA = (unsigned short*)alloc((size_t)U_ * Bc * 512 * 2);
    unsigned short* bufB = (unsigned short*)alloc((size_t)U_ * Bc * 512 * 2);

    prep_kernel<<<1, 64, 0, stream>>>(p1, p2, pf, b2, P1n, P2n, wfin, cconst);
    transpose_w<<<dim3(16, 16, 8), 256, 0, stream>>>(W0, W0t, 512, 512, nullptr);
    transpose_w<<<dim3(16, 16, 8), 256, 0, stream>>>(W1, W1t, 512, 512, nullptr);
    transpose_w<<<dim3(2, 16, 8), 256, 0, stream>>>(W2, W2t, NC_, NCP_, wfin);
    convert_x<<<dim3(B_ * IN_ / 8 / 256), 256, 0, stream>>>(x, xb, (long)B_ * IN_);

    const long plane = (long)Bc * 512;
    for (int bb = 0; bb < B_; bb += Bc) {
        gemm_h<<<dim3(4, Bc / 128, 8), 256, 0, stream>>>(
            xb + (long)bb * 512, 0L, W0t, b0, bufA, plane);
        aggregate<<<dim3(Bc / 4), 256, 0, stream>>>(bufA, bufB, P1n, plane);
        gemm_h<<<dim3(4, Bc / 128, 8), 256, 0, stream>>>(
            bufB, plane, W1t, b1, bufA, plane);
        aggregate<<<dim3(Bc / 4), 256, 0, stream>>>(bufA, bufB, P2n, plane);
        gemm_out<<<dim3(Bc / 64), 256, 0, stream>>>(
            bufB, plane, W2t, cconst, out + (long)bb * NC_);
    }
}

// Round 2
// 427.090 us; speedup vs baseline: 1.2077x; 1.2077x over previous
//
#include <hip/hip_runtime.h>

#define U_   8
#define B_   16384
#define NC_  62

typedef __attribute__((ext_vector_type(8))) short bfrag;   // 8 bf16 (4 VGPRs)
typedef __attribute__((ext_vector_type(4))) float facc;    // 4 fp32 acc

__device__ __forceinline__ float bf2f(unsigned int lo16) {
    union { unsigned int i; float f; } v;
    v.i = lo16 << 16;
    return v.f;
}
__device__ __forceinline__ unsigned short f2bf(float f) {
    unsigned int x = __float_as_uint(f);
    return (unsigned short)((x + 0x7fffu + ((x >> 16) & 1u)) >> 16);
}
__device__ __forceinline__ void gl2lds16(const void* g, void* l) {
    __builtin_amdgcn_global_load_lds(
        (const __attribute__((address_space(1))) void*)g,
        (__attribute__((address_space(3))) void*)l, 16, 0, 0);
}

// ---------------------------------------------------------------------------
// prep: normalized policies, final per-unit weights, folded output bias
// ---------------------------------------------------------------------------
__global__ void prep_kernel(const float* __restrict__ p1, const float* __restrict__ p2,
                            const float* __restrict__ pf, const float* __restrict__ b2,
                            float* __restrict__ P1n, float* __restrict__ P2n,
                            float* __restrict__ wfin, float* __restrict__ cconst)
{
    int t = threadIdx.x;
    if (t >= 64) return;
    int row = t >> 3;
    float s1 = 0.f, s2 = 0.f;
    for (int f = 0; f < 8; f++) { s1 += p1[row * 8 + f]; s2 += p2[row * 8 + f]; }
    P1n[t] = p1[t] * (s1 > 0.f ? 1.f / s1 : 1.f);
    P2n[t] = p2[t] * (s2 > 0.f ? 1.f / s2 : 1.f);
    float d = 0.f;
    for (int j = 0; j < 8; j++) d += pf[j];
    float inv = d > 0.f ? 1.f / d : 1.f;
    float wv[8];
    for (int j = 0; j < 8; j++) {
        float v = pf[j];
        for (int i = j; i < 8; i++) v *= inv;   // inv applied (8-j) times
        wv[j] = v;
    }
    if (t < 8) wfin[t] = wv[t];
    float cc = 0.f;
    if (t < NC_) for (int u = 0; u < 8; u++) cc += wv[u] * b2[u * NC_ + t];
    cconst[t] = cc;
}

// ---------------------------------------------------------------------------
// reorder_w0: W0 [u][k=512][n=512] fp32 -> W0r[n'][k] bf16,
//             n' = (n>>4)*128 + u*16 + (n&15)  (8-unit column groups)
// ---------------------------------------------------------------------------
__global__ __launch_bounds__(256) void reorder_w0(
    const float* __restrict__ W0, unsigned short* __restrict__ W0r)
{
    __shared__ float tile[32][33];
    const int u  = blockIdx.z;
    const int n0 = blockIdx.x * 32, k0 = blockIdx.y * 32;
    const int tx = threadIdx.x & 31, ty = threadIdx.x >> 5;
    const float* Wb = W0 + (long)u * 512 * 512;
#pragma unroll
    for (int i = 0; i < 4; i++)
        tile[ty + i * 8][tx] = Wb[(long)(k0 + ty + i * 8) * 512 + n0 + tx];
    __syncthreads();
#pragma unroll
    for (int i = 0; i < 4; i++) {
        int n = n0 + ty + i * 8, k = k0 + tx;
        int np = (n >> 4) * 128 + u * 16 + (n & 15);
        W0r[(long)np * 512 + k] = f2bf(tile[tx][ty + i * 8]);
    }
}

// ---------------------------------------------------------------------------
// transpose_w: W [u][k=512][n=512] fp32 -> Wt [u][n][k] bf16
// ---------------------------------------------------------------------------
__global__ __launch_bounds__(256) void transpose_w(
    const float* __restrict__ W, unsigned short* __restrict__ Wt)
{
    __shared__ float tile[32][33];
    const int u  = blockIdx.z;
    const int n0 = blockIdx.x * 32, k0 = blockIdx.y * 32;
    const int tx = threadIdx.x & 31, ty = threadIdx.x >> 5;
    const float* Wb = W + (long)u * 512 * 512;
#pragma unroll
    for (int i = 0; i < 4; i++)
        tile[ty + i * 8][tx] = Wb[(long)(k0 + ty + i * 8) * 512 + n0 + tx];
    __syncthreads();
    unsigned short* Wo = Wt + (long)u * 512 * 512;
#pragma unroll
    for (int i = 0; i < 4; i++) {
        int n = n0 + ty + i * 8, k = k0 + tx;
        Wo[(long)n * 512 + k] = f2bf(tile[tx][ty + i * 8]);
    }
}

// ---------------------------------------------------------------------------
// wout_build: Woutt[c][f*512+k] = sum_u wfin[u]*P2n[u,f]*W2[u][k][c]  (c<62)
// ---------------------------------------------------------------------------
__global__ __launch_bounds__(256) void wout_build(
    const float* __restrict__ W2, const float* __restrict__ P2n,
    const float* __restrict__ wfin, unsigned short* __restrict__ Woutt)
{
    const int c   = threadIdx.x & 63;
    const int row = blockIdx.x * 4 + (threadIdx.x >> 6);   // [0,4096)
    const int f = row >> 9, k = row & 511;
    float s = 0.f;
    if (c < NC_) {
#pragma unroll
        for (int u = 0; u < 8; u++)
            s += wfin[u] * P2n[u * 8 + f] * W2[((long)u * 512 + k) * NC_ + c];
    }
    Woutt[(long)c * 4096 + row] = f2bf(s);
}

// ---------------------------------------------------------------------------
// x fp32 -> bf16, 8 elems/thread
// ---------------------------------------------------------------------------
__global__ __launch_bounds__(256) void convert_x(
    const float* __restrict__ x, unsigned short* __restrict__ xb, long n)
{
    long i = ((long)blockIdx.x * 256 + threadIdx.x) * 8;
    if (i >= n) return;
    const float4* xp = (const float4*)(x + i);
    float4 a = xp[0], b = xp[1];
    uint4 o;
    o.x = f2bf(a.x) | ((unsigned)f2bf(a.y) << 16);
    o.y = f2bf(a.z) | ((unsigned)f2bf(a.w) << 16);
    o.z = f2bf(b.x) | ((unsigned)f2bf(b.y) << 16);
    o.w = f2bf(b.z) | ((unsigned)f2bf(b.w) << 16);
    *(uint4*)(xb + i) = o;
}

// ---------------------------------------------------------------------------
// gemm0_mix: 128x128 tile of h0 = relu(x@W0r + b0); epilogue mixes 8 units
// with P1n and writes a1cat [rows][4096] directly.
// Block cols = 8u x 16 feature (group ng). XCD-swizzled m-windows.
// ---------------------------------------------------------------------------
__global__ __launch_bounds__(256) void gemm0_mix(
    const unsigned short* __restrict__ xb, const unsigned short* __restrict__ W0r,
    const float* __restrict__ b0, const float* __restrict__ P1n,
    unsigned short* __restrict__ a1, int Mb)
{
    __shared__ __align__(16) unsigned short sm[128 * 130];  // 33280 B
    unsigned short* sA = sm;             // 128x32
    unsigned short* sB = sm + 128 * 32;  // 128x32

    const int tid = threadIdx.x, w = tid >> 6, lane = tid & 63;
    // XCD-locality swizzle: flat%8 ~ XCD; give each XCD an m-window, n outer
    const int flat = blockIdx.x + 32 * blockIdx.y;
    const int xcd = flat & 7, seq = flat >> 3;
    const int win = Mb >> 3;
    const int ng = seq / win, mloc = seq % win;
    const int mb = xcd * win + mloc;
    const long mBase = (long)mb * 128;
    const int nBase = ng * 128;

    const unsigned short* Bb = W0r + (long)nBase * 512;
    const int j0 = 2 * w, j1 = 2 * w + 1;
    const int rr0 = 16 * j0 + (lane >> 2), rr1 = 16 * j1 + (lane >> 2);
    const int c8 = (lane & 3) * 8;
    const unsigned short* gA0 = xb + (mBase + rr0) * 512 + c8;
    const unsigned short* gA1 = xb + (mBase + rr1) * 512 + c8;
    const unsigned short* gB0 = Bb + (long)rr0 * 512 + c8;
    const unsigned short* gB1 = Bb + (long)rr1 * 512 + c8;
    unsigned short *lA0 = sA + j0 * 512, *lA1 = sA + j1 * 512;
    unsigned short *lB0 = sB + j0 * 512, *lB1 = sB + j1 * 512;

    const int wm = w >> 1, wn = w & 1, r = lane & 15, q = lane >> 4;

    facc acc[4][4];
#pragma unroll
    for (int i = 0; i < 4; i++)
#pragma unroll
        for (int j = 0; j < 4; j++) acc[i][j] = (facc){0.f, 0.f, 0.f, 0.f};

    for (int k0 = 0; k0 < 512; k0 += 32) {
        __syncthreads();
        gl2lds16(gA0 + k0, lA0);
        gl2lds16(gA1 + k0, lA1);
        gl2lds16(gB0 + k0, lB0);
        gl2lds16(gB1 + k0, lB1);
        __syncthreads();
        bfrag aF[4], bF[4];
#pragma unroll
        for (int mt = 0; mt < 4; mt++)
            aF[mt] = *(const bfrag*)&sA[(wm * 64 + mt * 16 + r) * 32 + q * 8];
#pragma unroll
        for (int nt = 0; nt < 4; nt++)
            bF[nt] = *(const bfrag*)&sB[(wn * 64 + nt * 16 + r) * 32 + q * 8];
#pragma unroll
        for (int mt = 0; mt < 4; mt++)
#pragma unroll
            for (int nt = 0; nt < 4; nt++)
                acc[mt][nt] = __builtin_amdgcn_mfma_f32_16x16x32_bf16(
                    aF[mt], bF[nt], acc[mt][nt], 0, 0, 0);
    }

    __syncthreads();   // done with sA/sB region before overlaying T

    // stage relu(h0)+bias into T[col][row], col-major, stride 130 (even)
#pragma unroll
    for (int nt = 0; nt < 4; nt++) {
        const int cl = wn * 64 + nt * 16 + r;      // local col
        const int u = cl >> 4, i = cl & 15;
        const float bv = b0[u * 512 + ng * 16 + i];
#pragma unroll
        for (int mt = 0; mt < 4; mt++) {
            const int row0 = wm * 64 + mt * 16 + q * 4;
            float v0 = acc[mt][nt][0] + bv; v0 = v0 > 0.f ? v0 : 0.f;
            float v1 = acc[mt][nt][1] + bv; v1 = v1 > 0.f ? v1 : 0.f;
            float v2 = acc[mt][nt][2] + bv; v2 = v2 > 0.f ? v2 : 0.f;
            float v3 = acc[mt][nt][3] + bv; v3 = v3 > 0.f ? v3 : 0.f;
            unsigned int p01 = f2bf(v0) | ((unsigned)f2bf(v1) << 16);
            unsigned int p23 = f2bf(v2) | ((unsigned)f2bf(v3) << 16);
            *(unsigned int*)(sm + cl * 130 + row0)     = p01;
            *(unsigned int*)(sm + cl * 130 + row0 + 2) = p23;
        }
    }
    __syncthreads();

    // mix: a1[t][b][d] = sum_u P1n[t,u] * h0[u][b][d]
    float pw[64];
#pragma unroll
    for (int i = 0; i < 64; i++) pw[i] = P1n[i];   // uniform -> scalar loads
    const int ii = tid & 15;
    const int rb = (tid >> 4) * 8;
    const int dcol = ng * 16 + ii;
#pragma unroll
    for (int j = 0; j < 8; j++) {
        const int row = rb + j;
        float h[8];
#pragma unroll
        for (int u = 0; u < 8; u++)
            h[u] = bf2f((unsigned int)sm[(u * 16 + ii) * 130 + row]);
        unsigned short* orow = a1 + (mBase + row) * 4096 + dcol;
#pragma unroll
        for (int t = 0; t < 8; t++) {
            float s = 0.f;
#pragma unroll
            for (int u = 0; u < 8; u++) s = fmaf(pw[t * 8 + u], h[u], s);
            orow[t * 512] = f2bf(s);
        }
    }
}

// ---------------------------------------------------------------------------
// gemm_h (layer 1): h1[u] = relu(a1[u] @ W1t[u]^T + b1[u]), interleaved layout
// A = a1cat [rows][4096] (unit u at col offset u*512), C = h1cat same layout.
// XCD swizzle: 4-n-groups + per-XCD m windows.
// ---------------------------------------------------------------------------
__global__ __launch_bounds__(256) void gemm_h(
    const unsigned short* __restrict__ A,
    const unsigned short* __restrict__ W1t,
    const float* __restrict__ bias,
    unsigned short* __restrict__ C, int Mb)
{
    __shared__ __align__(16) unsigned short sA[128 * 32];
    __shared__ __align__(16) unsigned short sB[128 * 32];
    const int tid = threadIdx.x, w = tid >> 6, lane = tid & 63;

    const int flat = blockIdx.x + 4 * (blockIdx.y + Mb * blockIdx.z);
    const int xcd = flat & 7, seq = flat >> 3;
    const int n = seq & 3;
    const int pg = (seq >> 2) * 8 + xcd;
    const int u = pg / Mb, mb = pg % Mb;
    const long mBase = (long)mb * 128;
    const int nBase = n * 128;

    const unsigned short* Ab = A + u * 512;
    const unsigned short* Bb = W1t + ((long)u * 512 + nBase) * 512;

    const int j0 = 2 * w, j1 = 2 * w + 1;
    const int rr0 = 16 * j0 + (lane >> 2), rr1 = 16 * j1 + (lane >> 2);
    const int c8 = (lane & 3) * 8;
    const unsigned short* gA0 = Ab + (mBase + rr0) * 4096 + c8;
    const unsigned short* gA1 = Ab + (mBase + rr1) * 4096 + c8;
    const unsigned short* gB0 = Bb + (long)rr0 * 512 + c8;
    const unsigned short* gB1 = Bb + (long)rr1 * 512 + c8;
    unsigned short *lA0 = sA + j0 * 512, *lA1 = sA + j1 * 512;
    unsigned short *lB0 = sB + j0 * 512, *lB1 = sB + j1 * 512;

    const int wm = w >> 1, wn = w & 1, r = lane & 15, q = lane >> 4;

    facc acc[4][4];
#pragma unroll
    for (int i = 0; i < 4; i++)
#pragma unroll
        for (int j = 0; j < 4; j++) acc[i][j] = (facc){0.f, 0.f, 0.f, 0.f};

    for (int k0 = 0; k0 < 512; k0 += 32) {
        __syncthreads();
        gl2lds16(gA0 + k0, lA0);
        gl2lds16(gA1 + k0, lA1);
        gl2lds16(gB0 + k0, lB0);
        gl2lds16(gB1 + k0, lB1);
        __syncthreads();
        bfrag aF[4], bF[4];
#pragma unroll
        for (int mt = 0; mt < 4; mt++)
            aF[mt] = *(const bfrag*)&sA[(wm * 64 + mt * 16 + r) * 32 + q * 8];
#pragma unroll
        for (int nt = 0; nt < 4; nt++)
            bF[nt] = *(const bfrag*)&sB[(wn * 64 + nt * 16 + r) * 32 + q * 8];
#pragma unroll
        for (int mt = 0; mt < 4; mt++)
#pragma unroll
            for (int nt = 0; nt < 4; nt++)
                acc[mt][nt] = __builtin_amdgcn_mfma_f32_16x16x32_bf16(
                    aF[mt], bF[nt], acc[mt][nt], 0, 0, 0);
    }

    const float* bu = bias + u * 512;
#pragma unroll
    for (int nt = 0; nt < 4; nt++) {
        const int col = nBase + wn * 64 + nt * 16 + r;
        const float bv = bu[col];
#pragma unroll
        for (int mt = 0; mt < 4; mt++) {
#pragma unroll
            for (int rg = 0; rg < 4; rg++) {
                const long gm = mBase + wm * 64 + mt * 16 + q * 4 + rg;
                float v = acc[mt][nt][rg] + bv;
                v = v > 0.f ? v : 0.f;
                C[gm * 4096 + u * 512 + col] = f2bf(v);
            }
        }
    }
}

// ---------------------------------------------------------------------------
// gemm_out: out[b,c] = sum_k h1cat[b][k] * Woutt[c][k] + cconst[c], K=4096
// 64x64 tile, contiguous K.
// ---------------------------------------------------------------------------
__global__ __launch_bounds__(256) void gemm_out(
    const unsigned short* __restrict__ A,
    const unsigned short* __restrict__ Bt,
    const float* __restrict__ cconst,
    float* __restrict__ out)
{
    __shared__ __align__(16) unsigned short sA[64 * 32];
    __shared__ __align__(16) unsigned short sB[64 * 32];
    const int tid = threadIdx.x, w = tid >> 6, lane = tid & 63;
    const long mBase = (long)blockIdx.x * 64;
    const int row = w * 16 + (lane >> 2);
    const int c8 = (lane & 3) * 8;
    const int wm = w >> 1, wn = w & 1, r = lane & 15, q = lane >> 4;

    const unsigned short* gA = A + (mBase + row) * 4096 + c8;
    const unsigned short* gB = Bt + (long)row * 4096 + c8;
    unsigned short* lA = sA + w * 512;
    unsigned short* lB = sB + w * 512;

    facc acc[2][2];
#pragma unroll
    for (int i = 0; i < 2; i++)
#pragma unroll
        for (int j = 0; j < 2; j++) acc[i][j] = (facc){0.f, 0.f, 0.f, 0.f};

    for (int k0 = 0; k0 < 4096; k0 += 32) {
        __syncthreads();
        gl2lds16(gA + k0, lA);
        gl2lds16(gB + k0, lB);
        __syncthreads();
        bfrag aF[2], bF[2];
#pragma unroll
        for (int mt = 0; mt < 2; mt++)
            aF[mt] = *(const bfrag*)&sA[(wm * 32 + mt * 16 + r) * 32 + q * 8];
#pragma unroll
        for (int nt = 0; nt < 2; nt++)
            bF[nt] = *(const bfrag*)&sB[(wn * 32 + nt * 16 + r) * 32 + q * 8];
#pragma unroll
        for (int mt = 0; mt < 2; mt++)
#pragma unroll
            for (int nt = 0; nt < 2; nt++)
                acc[mt][nt] = __builtin_amdgcn_mfma_f32_16x16x32_bf16(
                    aF[mt], bF[nt], acc[mt][nt], 0, 0, 0);
    }

#pragma unroll
    for (int nt = 0; nt < 2; nt++) {
        const int c = wn * 32 + nt * 16 + r;
        if (c < NC_) {
            const float cc = cconst[c];
#pragma unroll
            for (int mt = 0; mt < 2; mt++) {
#pragma unroll
                for (int rg = 0; rg < 4; rg++) {
                    const long gm = mBase + wm * 32 + mt * 16 + q * 4 + rg;
                    out[gm * NC_ + c] = acc[mt][nt][rg] + cc;
                }
            }
        }
    }
}

// ---------------------------------------------------------------------------
extern "C" void kernel_launch(void* const* d_in, const int* in_sizes, int n_in,
                              void* d_out, int out_size, void* d_ws, size_t ws_size,
                              hipStream_t stream)
{
    const float* x  = (const float*)d_in[0];
    const float* p1 = (const float*)d_in[1];
    const float* p2 = (const float*)d_in[2];
    const float* pf = (const float*)d_in[3];
    const float* W0 = (const float*)d_in[4];
    const float* b0 = (const float*)d_in[5];
    const float* W1 = (const float*)d_in[6];
    const float* b1 = (const float*)d_in[7];
    const float* W2 = (const float*)d_in[8];
    const float* b2 = (const float*)d_in[9];
    float* out = (float*)d_out;

    char* ws = (char*)d_ws;
    size_t off = 0;
    auto alloc = [&](size_t bytes) -> void* {
        void* p = ws + off;
        off += (bytes + 255) & ~(size_t)255;
        return p;
    };
    float* P1n    = (float*)alloc(64 * sizeof(float));
    float* P2n    = (float*)alloc(64 * sizeof(float));
    float* wfin   = (float*)alloc(8 * sizeof(float));
    float* cconst = (float*)alloc(64 * sizeof(float));
    unsigned short* W0r   = (unsigned short*)alloc((size_t)4096 * 512 * 2);
    unsigned short* W1t   = (unsigned short*)alloc((size_t)U_ * 512 * 512 * 2);
    unsigned short* Woutt = (unsigned short*)alloc((size_t)64 * 4096 * 2);
    unsigned short* xb    = (unsigned short*)alloc((size_t)B_ * 512 * 2);

    size_t remain = ws_size > off ? ws_size - off : 0;
    int Bc = 1024;
    for (int cand = B_; cand >= 1024; cand >>= 1) {
        if (2ull * (size_t)cand * 4096 * 2 + 512 <= remain) { Bc = cand; break; }
    }
    unsigned short* a1 = (unsigned short*)alloc((size_t)Bc * 4096 * 2);
    unsigned short* h1 = (unsigned short*)alloc((size_t)Bc * 4096 * 2);

    prep_kernel<<<1, 64, 0, stream>>>(p1, p2, pf, b2, P1n, P2n, wfin, cconst);
    reorder_w0<<<dim3(16, 16, 8), 256, 0, stream>>>(W0, W0r);
    transpose_w<<<dim3(16, 16, 8), 256, 0, stream>>>(W1, W1t);
    wout_build<<<dim3(1024), 256, 0, stream>>>(W2, P2n, wfin, Woutt);
    convert_x<<<dim3(B_ * 512 / 8 / 256), 256, 0, stream>>>(x, xb, (long)B_ * 512);

    const int Mb = Bc / 128;
    for (int bb = 0; bb < B_; bb += Bc) {
        gemm0_mix<<<dim3(32, Mb), 256, 0, stream>>>(
            xb + (long)bb * 512, W0r, b0, P1n, a1, Mb);
        gemm_h<<<dim3(4, Mb, 8), 256, 0, stream>>>(a1, W1t, b1, h1, Mb);
        gemm_out<<<dim3(Bc / 64), 256, 0, stream>>>(
            h1, Woutt, cconst, out + (long)bb * NC_);
    }
}